// Round 5
// baseline (109.654 us; speedup 1.0000x reference)
//
#include <hip/hip_runtime.h>

#define N_NODES 3072
#define IN_DIM 512
#define OUT_DIM 64
#define HEADS 8
#define NEG_SLOPE 0.2f
#define MAX_E 128            // Poisson(~31) edges/row; 128 is >17 sigma

typedef __attribute__((ext_vector_type(8))) short bf16x8;
typedef __attribute__((ext_vector_type(4))) float f32x4;

#define XFRAG_TILES (N_NODES / 16)     // 192 row-tiles
#define KTILES (IN_DIM / 32)           // 16 k-tiles
#define XFRAG_THREADS (XFRAG_TILES * KTILES * 64)   // 196608
#define WFRAG_THREADS (HEADS * KTILES * 4 * 64)     // 32768
#define PREP_BLOCKS ((XFRAG_THREADS + WFRAG_THREADS) / 256)  // 896

__device__ inline unsigned short f2bf(float f) {   // RNE float->bf16
    union { float f; unsigned u; } v; v.f = f;
    unsigned r = (v.u + 0x7FFF + ((v.u >> 16) & 1)) >> 16;
    return (unsigned short)r;
}

// Kernel 1: adj edge-compaction scan (blocks 0..3071, one row each) MERGED
// with fragment prep (blocks 3072..3967). The two are independent: scan is
// pure HBM streaming (37.7 MB — the long pole), prep is VALU/convert-heavy
// with only 11 MB of traffic. Merging removes one serialized dispatch (~3 us
// exposed in R0/R4) and hides prep's bandwidth under the scan stream.
// Scan blocks come FIRST so the 37.7 MB stream starts at t=0.
__global__ __launch_bounds__(256) void gat_prep_scan(
    const float* __restrict__ x, const float* __restrict__ W,
    const float* __restrict__ adj,
    short* __restrict__ xfrag, short* __restrict__ wfrag,
    int* __restrict__ e_idx, int* __restrict__ e_cnt) {
    __shared__ int s_idx[MAX_E];
    __shared__ int s_cnt;

    const int b = blockIdx.x;
    const int t = threadIdx.x;

    if (b < N_NODES) {
        // ---- edge compaction for row i: find nonzeros, write packed list
        const int i = b;
        if (t == 0) s_cnt = 0;
        __syncthreads();

        const float4* arow4 = (const float4*)(adj + (size_t)i * N_NODES);
#pragma unroll
        for (int it = 0; it < 3; ++it) {
            const int jj = t + it * 256;        // 768 float4 = 3072 cols
            float4 v = arow4[jj];
            const int j = jj * 4;
            if (v.x > 0.f) { int s = atomicAdd(&s_cnt, 1); if (s < MAX_E) s_idx[s] = j; }
            if (v.y > 0.f) { int s = atomicAdd(&s_cnt, 1); if (s < MAX_E) s_idx[s] = j + 1; }
            if (v.z > 0.f) { int s = atomicAdd(&s_cnt, 1); if (s < MAX_E) s_idx[s] = j + 2; }
            if (v.w > 0.f) { int s = atomicAdd(&s_cnt, 1); if (s < MAX_E) s_idx[s] = j + 3; }
        }
        __syncthreads();
        const int E = min(s_cnt, MAX_E);        // self-loop -> E >= 1
        if (t < E) e_idx[(size_t)i * MAX_E + t] = s_idx[t];
        if (t == 0) e_cnt[i] = E;
    } else {
        // ---- fragment prep (R0 known-good layout)
        // xfrag[rt][kt][lane][8]: lane l holds x[rt*16+(l&15)][kt*32+(l>>4)*8+j]
        // wfrag[head][kt][c][lane][8]: l holds W[head][kt*32+(l>>4)*8+j][c*16+(l&15)]
        const int tid = (b - N_NODES) * 256 + t;
        if (tid < XFRAG_THREADS) {
            int lane = tid & 63;
            int kt = (tid >> 6) & (KTILES - 1);
            int rt = tid >> 10;
            int m = rt * 16 + (lane & 15);
            int k0 = kt * 32 + (lane >> 4) * 8;
            const float4* xp = (const float4*)(x + (size_t)m * IN_DIM + k0);
            float4 v0 = xp[0], v1 = xp[1];
            bf16x8 r;
            r[0] = (short)f2bf(v0.x); r[1] = (short)f2bf(v0.y);
            r[2] = (short)f2bf(v0.z); r[3] = (short)f2bf(v0.w);
            r[4] = (short)f2bf(v1.x); r[5] = (short)f2bf(v1.y);
            r[6] = (short)f2bf(v1.z); r[7] = (short)f2bf(v1.w);
            ((bf16x8*)xfrag)[tid] = r;
        } else {
            int t2 = tid - XFRAG_THREADS;
            if (t2 < WFRAG_THREADS) {
                int lane = t2 & 63;
                int c = (t2 >> 6) & 3;
                int kt = (t2 >> 8) & (KTILES - 1);
                int head = t2 >> 12;
                int n = c * 16 + (lane & 15);
                int k0 = kt * 32 + (lane >> 4) * 8;
                const float* wp = W + ((size_t)head * IN_DIM + k0) * OUT_DIM + n;
                bf16x8 r;
#pragma unroll
                for (int j = 0; j < 8; ++j) r[j] = (short)f2bf(wp[(size_t)j * OUT_DIM]);
                ((bf16x8*)wfrag)[t2] = r;
            }
        }
    }
}

// Kernel 2: h[head] = x @ W[head] via direct-fragment MFMA (R0 known-good).
// Block = 4 waves = 32 rows x 64 cols, one head. Grid dim3(96,8): linear id
// = rtp + head*96, 96%8==0 -> all 8 heads of a row-tile land on one XCD ->
// xfrag L2-shared. Epilogue writes h bf16 NODE-MAJOR hb[n][head*64+col]
// (L2-resident 3.1 MB for the agg gather) + fp32 f_src/f_dst via LDS tile.
__global__ __launch_bounds__(256) void gat_proj(
    const short* __restrict__ xfrag, const short* __restrict__ wfrag,
    const float* __restrict__ a_src, const float* __restrict__ a_dst,
    unsigned short* __restrict__ hb, float* __restrict__ fsrc, float* __restrict__ fdst) {
    __shared__ float hs[32][OUT_DIM + 1];

    const int t = threadIdx.x;
    const int lane = t & 63;
    const int w = t >> 6;
    const int head = blockIdx.y;
    const int m0 = blockIdx.x * 32;
    const int rt0 = blockIdx.x * 2;

    const bf16x8* xa = (const bf16x8*)xfrag + (size_t)rt0 * 16 * 64 + lane;
    const bf16x8* wb = (const bf16x8*)wfrag + ((size_t)head * KTILES * 4 + w) * 64 + lane;

    f32x4 acc0 = {0.f, 0.f, 0.f, 0.f};
    f32x4 acc1 = {0.f, 0.f, 0.f, 0.f};
#pragma unroll
    for (int kt = 0; kt < KTILES; ++kt) {
        bf16x8 a0 = xa[kt * 64];            // rows m0..m0+15
        bf16x8 a1 = xa[(16 + kt) * 64];     // rows m0+16..m0+31
        bf16x8 b  = wb[kt * 4 * 64];        // cols w*16..w*16+15
        acc0 = __builtin_amdgcn_mfma_f32_16x16x32_bf16(a0, b, acc0, 0, 0, 0);
        acc1 = __builtin_amdgcn_mfma_f32_16x16x32_bf16(a1, b, acc1, 0, 0, 0);
    }

    // D mapping: col=lane&15 (within tile), row=(lane>>4)*4+i
    const int col = w * 16 + (lane & 15);
    const int r0 = (lane >> 4) * 4;
    unsigned short* hp = hb + (size_t)m0 * (HEADS * OUT_DIM) + head * OUT_DIM + col;
#pragma unroll
    for (int i2 = 0; i2 < 4; ++i2) {
        hs[r0 + i2][col] = acc0[i2];
        hs[r0 + 16 + i2][col] = acc1[i2];
        hp[(size_t)(r0 + i2) * (HEADS * OUT_DIM)] = f2bf(acc0[i2]);
        hp[(size_t)(r0 + 16 + i2) * (HEADS * OUT_DIM)] = f2bf(acc1[i2]);
    }
    __syncthreads();

    // f-pass: threads 0..127 -> f_src, 128..255 -> f_dst (fp32 from LDS tile)
    {
        const float* av = (t < 128 ? a_src : a_dst) + head * OUT_DIM;
        const int tt = t & 127;
        const int row = tt >> 2, part = tt & 3;
        float s = 0.f;
#pragma unroll
        for (int n = 0; n < 16; ++n) s += hs[row][part * 16 + n] * av[part * 16 + n];
        s += __shfl_xor(s, 1, 64);
        s += __shfl_xor(s, 2, 64);
        if (part == 0) {
            float* dst = (t < 128 ? fsrc : fdst);
            dst[head * N_NODES + m0 + row] = s;
        }
    }
}

// Kernel 3: softmax + gather-aggregate from precompacted edge lists (R4
// known-good). One block per row i. Wave w handles heads {2w, 2w+1}: lanes
// 0..31 -> head 2w, lanes 32..63 -> head 2w+1, each lane owning 2 output
// dims. Gather = ONE coalesced 256B dword load per wave per edge.
__global__ __launch_bounds__(256) void gat_agg(
    const int* __restrict__ e_idx, const int* __restrict__ e_cnt,
    const unsigned short* __restrict__ hb,
    const float* __restrict__ fsrc, const float* __restrict__ fdst,
    float* __restrict__ out) {
    __shared__ int s_idx[MAX_E];
    __shared__ float s_p[HEADS][MAX_E];

    const int i = blockIdx.x;
    const int t = threadIdx.x;
    const int E = e_cnt[i];                     // uniform scalar load
    if (t < E) s_idx[t] = e_idx[(size_t)i * MAX_E + t];
    __syncthreads();

    const int w = t >> 6;
    const int lane = t & 63;
    const int half = lane >> 5;                 // 0 or 1
    const int sl = lane & 31;                   // sub-lane within half
    const int head = 2 * w + half;

    const float fi = fsrc[head * N_NODES + i];

    // pass 1: logits + half-wave max
    float m = -1e30f;
    for (int k = sl; k < E; k += 32) {
        float e = fi + fdst[head * N_NODES + s_idx[k]];
        e = e > 0.f ? e : NEG_SLOPE * e;
        s_p[head][k] = e;
        m = fmaxf(m, e);
    }
#pragma unroll
    for (int o = 16; o; o >>= 1) m = fmaxf(m, __shfl_xor(m, o, 64));

    // pass 2: exp + half-wave sum
    float sum = 0.f;
    for (int k = sl; k < E; k += 32) {
        float p = __expf(s_p[head][k] - m);
        s_p[head][k] = p;
        sum += p;
    }
#pragma unroll
    for (int o = 16; o; o >>= 1) sum += __shfl_xor(sum, o, 64);
    const float inv = 1.f / sum;

    __syncthreads();   // fence striped s_p writes before all-k reads

    // gather-aggregate: lane owns dims {sl*2, sl*2+1} of its head.
    const unsigned short* hbase = hb + head * OUT_DIM + sl * 2;
    float a0 = 0.f, a1 = 0.f;
#pragma unroll 8
    for (int k = 0; k < E; ++k) {
        const int j = s_idx[k];
        const float p = s_p[head][k];
        const unsigned u = *(const unsigned*)(hbase + (size_t)j * (HEADS * OUT_DIM));
        a0 = fmaf(p, __uint_as_float(u << 16), a0);
        a1 = fmaf(p, __uint_as_float(u & 0xffff0000u), a1);
    }
    float2 r = {a0 * inv, a1 * inv};
    *(float2*)(out + (size_t)i * (HEADS * OUT_DIM) + head * OUT_DIM + sl * 2) = r;
}

extern "C" void kernel_launch(void* const* d_in, const int* in_sizes, int n_in,
                              void* d_out, int out_size, void* d_ws, size_t ws_size,
                              hipStream_t stream) {
    const float* x     = (const float*)d_in[0];
    const float* adj   = (const float*)d_in[1];
    const float* W     = (const float*)d_in[2];
    const float* a_src = (const float*)d_in[3];
    const float* a_dst = (const float*)d_in[4];
    float* out = (float*)d_out;

    float* fsrc = (float*)d_ws;                               // [H,N]
    float* fdst = fsrc + HEADS * N_NODES;                     // [H,N]
    unsigned short* hb = (unsigned short*)(fdst + HEADS * N_NODES);   // [N, H*64] bf16
    short* xfrag = (short*)(hb + (size_t)N_NODES * HEADS * OUT_DIM);
    short* wfrag = xfrag + (size_t)XFRAG_TILES * KTILES * 64 * 8;
    int* e_idx = (int*)(wfrag + (size_t)HEADS * KTILES * 4 * 64 * 8);  // [N, MAX_E]
    int* e_cnt = e_idx + (size_t)N_NODES * MAX_E;                      // [N]

    gat_prep_scan<<<N_NODES + PREP_BLOCKS, 256, 0, stream>>>(
        x, W, adj, xfrag, wfrag, e_idx, e_cnt);
    gat_proj<<<dim3(N_NODES / 32, HEADS), 256, 0, stream>>>(
        xfrag, wfrag, a_src, a_dst, hb, fsrc, fdst);
    gat_agg<<<N_NODES, 256, 0, stream>>>(e_idx, e_cnt, hb, fsrc, fdst, out);
}

// Round 6
// 107.258 us; speedup vs baseline: 1.0223x; 1.0223x over previous
//
#include <hip/hip_runtime.h>

#define N_NODES 3072
#define IN_DIM 512
#define OUT_DIM 64
#define HEADS 8
#define NEG_SLOPE 0.2f
#define MAX_E 128            // Poisson(~31) edges/row; 128 is >17 sigma
#define KTILES (IN_DIM / 32) // 16 k-tiles
#define PROJ_BLOCKS (N_NODES / 32 * HEADS)   // 768

typedef __attribute__((ext_vector_type(8))) short bf16x8;
typedef __attribute__((ext_vector_type(4))) float f32x4;

__device__ inline unsigned short f2bf(float f) {   // RNE float->bf16
    union { float f; unsigned u; } v; v.f = f;
    unsigned r = (v.u + 0x7FFF + ((v.u >> 16) & 1)) >> 16;
    return (unsigned short)r;
}

// Kernel 1: projection WITH INLINE PREP (blocks 0..767) co-dispatched with
// the adj edge-compaction scan (blocks 768..3839). No prep kernel, no
// fragment buffers in HBM.
//
// Proj block (head=b/96, rtp=b%96): stages its 32x512 x-tile fp32->bf16 into
// LDS in MFMA-fragment layout. Global reads are fully coalesced (32 B/lane
// along rows — R3's direct-fragment loads were 64 segments/inst, THE killer).
// LDS writes XOR-swizzled (lane ^= (kt&3)<<2): write = 4-way conflict
// (~1.6x, hidden under load latency), fragment read = contiguous permuted
// 1 KB/wave = conflict-free. W fragments built in-registers per kt from
// L2-hot fp32 W (R3's W path — 4x64B segments/inst, proven fine).
// hs epilogue tile OVERLAYS xs (sync before reuse). LDS = 32 KB -> 4 blk/CU.
// 96%8==0 -> all 8 heads of a row-tile group share an XCD (x L2-local).
// Scan blocks backfill CUs and stream adj's 37.7 MB under proj's compute.
__global__ __launch_bounds__(256) void gat_proj_scan(
    const float* __restrict__ x, const float* __restrict__ W,
    const float* __restrict__ adj,
    const float* __restrict__ a_src, const float* __restrict__ a_dst,
    unsigned short* __restrict__ hb, float* __restrict__ fsrc,
    float* __restrict__ fdst, int* __restrict__ e_idx, int* __restrict__ e_cnt) {
    __shared__ __align__(16) char smem[32768];

    const int b = blockIdx.x;
    const int t = threadIdx.x;

    if (b < PROJ_BLOCKS) {
        short* xs = (short*)smem;           // [2][16][64] bf16x8 fragment tiles
        const int lane = t & 63;
        const int w = t >> 6;
        const int head = b / 96;
        const int rtp = b % 96;
        const int m0 = rtp * 32;

        // ---- stage x-tile: thread t loads row r = t>>3, 8 chunks of 8 cols.
        // chunk qq: cols k0 = (t&7)*8 + qq*64 (32 B contiguous per lane;
        // wave = 8 rows x 256 B runs = 8 segments/inst).
        // Fragment target: kt = k0>>5 = (c8>>2)+qq*2; lane16 = (r&15)|((c8&3)<<4);
        // all 8 cols share one bf16x8 slot (j = 0..7). Verified algebraically:
        // kt*32 + ((c8&3))*8 + j == k0 + j.
        {
            const int r = t >> 3, c8 = t & 7;
            const float* xrow = x + (size_t)(m0 + r) * IN_DIM;
#pragma unroll
            for (int qq = 0; qq < 8; ++qq) {
                const int k0 = c8 * 8 + qq * 64;
                const float4* xp = (const float4*)(xrow + k0);
                float4 v0 = xp[0], v1 = xp[1];
                bf16x8 rv;
                rv[0] = (short)f2bf(v0.x); rv[1] = (short)f2bf(v0.y);
                rv[2] = (short)f2bf(v0.z); rv[3] = (short)f2bf(v0.w);
                rv[4] = (short)f2bf(v1.x); rv[5] = (short)f2bf(v1.y);
                rv[6] = (short)f2bf(v1.z); rv[7] = (short)f2bf(v1.w);
                const int kt = (c8 >> 2) + qq * 2;
                const int l16 = (r & 15) | ((c8 & 3) << 4);
                const int idx16 = ((r >> 4) * 16 + kt) * 64 + (l16 ^ ((kt & 3) << 2));
                ((bf16x8*)xs)[idx16] = rv;
            }
        }
        __syncthreads();

        // ---- MFMA k-loop: A from LDS fragments, B built in-regs from W fp32
        const int colr = lane & 15;
        const int kq = lane >> 4;
        const float* wbase = W + ((size_t)head * IN_DIM + kq * 8) * OUT_DIM + w * 16 + colr;

        f32x4 acc0 = {0.f, 0.f, 0.f, 0.f};
        f32x4 acc1 = {0.f, 0.f, 0.f, 0.f};
#pragma unroll
        for (int kt = 0; kt < KTILES; ++kt) {   // FULL unroll: no runtime idx
            const float* wp = wbase + (size_t)kt * 32 * OUT_DIM;
            bf16x8 bv;
#pragma unroll
            for (int j = 0; j < 8; ++j) bv[j] = (short)f2bf(wp[(size_t)j * OUT_DIM]);
            const int sw = (kt & 3) << 2;
            bf16x8 a0 = ((const bf16x8*)xs)[kt * 64 + (lane ^ sw)];         // rows m0..+15
            bf16x8 a1 = ((const bf16x8*)xs)[(16 + kt) * 64 + (lane ^ sw)];  // rows m0+16..+31
            acc0 = __builtin_amdgcn_mfma_f32_16x16x32_bf16(a0, bv, acc0, 0, 0, 0);
            acc1 = __builtin_amdgcn_mfma_f32_16x16x32_bf16(a1, bv, acc1, 0, 0, 0);
        }
        __syncthreads();    // all waves done reading xs -> safe to overlay hs

        // ---- epilogue (R4 known-good): D col=lane&15, row=(lane>>4)*4+i
        float (*hs)[OUT_DIM + 1] = (float (*)[OUT_DIM + 1])smem;
        const int col = w * 16 + colr;
        const int r0 = kq * 4;
        unsigned short* hp = hb + (size_t)m0 * (HEADS * OUT_DIM) + head * OUT_DIM + col;
#pragma unroll
        for (int i2 = 0; i2 < 4; ++i2) {
            hs[r0 + i2][col] = acc0[i2];
            hs[r0 + 16 + i2][col] = acc1[i2];
            hp[(size_t)(r0 + i2) * (HEADS * OUT_DIM)] = f2bf(acc0[i2]);
            hp[(size_t)(r0 + 16 + i2) * (HEADS * OUT_DIM)] = f2bf(acc1[i2]);
        }
        __syncthreads();

        // f-pass: threads 0..127 -> f_src, 128..255 -> f_dst (fp32 LDS tile)
        const float* av = (t < 128 ? a_src : a_dst) + head * OUT_DIM;
        const int tt = t & 127;
        const int row = tt >> 2, part = tt & 3;
        float s = 0.f;
#pragma unroll
        for (int n = 0; n < 16; ++n) s += hs[row][part * 16 + n] * av[part * 16 + n];
        s += __shfl_xor(s, 1, 64);
        s += __shfl_xor(s, 2, 64);
        if (part == 0) {
            float* dst = (t < 128 ? fsrc : fdst);
            dst[head * N_NODES + m0 + row] = s;
        }
    } else {
        // ---- edge compaction for row i: find nonzeros, write packed list
        int* s_idx = (int*)smem;
        int* s_cnt = (int*)(smem + MAX_E * 4);
        const int i = b - PROJ_BLOCKS;
        if (t == 0) *s_cnt = 0;
        __syncthreads();

        const float4* arow4 = (const float4*)(adj + (size_t)i * N_NODES);
#pragma unroll
        for (int it = 0; it < 3; ++it) {
            const int jj = t + it * 256;        // 768 float4 = 3072 cols
            float4 v = arow4[jj];
            const int j = jj * 4;
            if (v.x > 0.f) { int s = atomicAdd(s_cnt, 1); if (s < MAX_E) s_idx[s] = j; }
            if (v.y > 0.f) { int s = atomicAdd(s_cnt, 1); if (s < MAX_E) s_idx[s] = j + 1; }
            if (v.z > 0.f) { int s = atomicAdd(s_cnt, 1); if (s < MAX_E) s_idx[s] = j + 2; }
            if (v.w > 0.f) { int s = atomicAdd(s_cnt, 1); if (s < MAX_E) s_idx[s] = j + 3; }
        }
        __syncthreads();
        const int E = min(*s_cnt, MAX_E);       // self-loop -> E >= 1
        if (t < E) e_idx[(size_t)i * MAX_E + t] = s_idx[t];
        if (t == 0) e_cnt[i] = E;
    }
}

// Kernel 2: softmax + gather-aggregate from precompacted edge lists (R4
// known-good). One block per row i. Wave w handles heads {2w, 2w+1}: lanes
// 0..31 -> head 2w, lanes 32..63 -> head 2w+1, each lane owning 2 output
// dims. Gather = ONE coalesced 256B dword load per wave per edge.
__global__ __launch_bounds__(256) void gat_agg(
    const int* __restrict__ e_idx, const int* __restrict__ e_cnt,
    const unsigned short* __restrict__ hb,
    const float* __restrict__ fsrc, const float* __restrict__ fdst,
    float* __restrict__ out) {
    __shared__ int s_idx[MAX_E];
    __shared__ float s_p[HEADS][MAX_E];

    const int i = blockIdx.x;
    const int t = threadIdx.x;
    const int E = e_cnt[i];                     // uniform scalar load
    if (t < E) s_idx[t] = e_idx[(size_t)i * MAX_E + t];
    __syncthreads();

    const int w = t >> 6;
    const int lane = t & 63;
    const int half = lane >> 5;                 // 0 or 1
    const int sl = lane & 31;                   // sub-lane within half
    const int head = 2 * w + half;

    const float fi = fsrc[head * N_NODES + i];

    // pass 1: logits + half-wave max
    float m = -1e30f;
    for (int k = sl; k < E; k += 32) {
        float e = fi + fdst[head * N_NODES + s_idx[k]];
        e = e > 0.f ? e : NEG_SLOPE * e;
        s_p[head][k] = e;
        m = fmaxf(m, e);
    }
#pragma unroll
    for (int o = 16; o; o >>= 1) m = fmaxf(m, __shfl_xor(m, o, 64));

    // pass 2: exp + half-wave sum
    float sum = 0.f;
    for (int k = sl; k < E; k += 32) {
        float p = __expf(s_p[head][k] - m);
        s_p[head][k] = p;
        sum += p;
    }
#pragma unroll
    for (int o = 16; o; o >>= 1) sum += __shfl_xor(sum, o, 64);
    const float inv = 1.f / sum;

    __syncthreads();   // fence striped s_p writes before all-k reads

    // gather-aggregate: lane owns dims {sl*2, sl*2+1} of its head.
    const unsigned short* hbase = hb + head * OUT_DIM + sl * 2;
    float a0 = 0.f, a1 = 0.f;
#pragma unroll 8
    for (int k = 0; k < E; ++k) {
        const int j = s_idx[k];
        const float p = s_p[head][k];
        const unsigned u = *(const unsigned*)(hbase + (size_t)j * (HEADS * OUT_DIM));
        a0 = fmaf(p, __uint_as_float(u << 16), a0);
        a1 = fmaf(p, __uint_as_float(u & 0xffff0000u), a1);
    }
    float2 r = {a0 * inv, a1 * inv};
    *(float2*)(out + (size_t)i * (HEADS * OUT_DIM) + head * OUT_DIM + sl * 2) = r;
}

extern "C" void kernel_launch(void* const* d_in, const int* in_sizes, int n_in,
                              void* d_out, int out_size, void* d_ws, size_t ws_size,
                              hipStream_t stream) {
    const float* x     = (const float*)d_in[0];
    const float* adj   = (const float*)d_in[1];
    const float* W     = (const float*)d_in[2];
    const float* a_src = (const float*)d_in[3];
    const float* a_dst = (const float*)d_in[4];
    float* out = (float*)d_out;

    float* fsrc = (float*)d_ws;                               // [H,N]
    float* fdst = fsrc + HEADS * N_NODES;                     // [H,N]
    unsigned short* hb = (unsigned short*)(fdst + HEADS * N_NODES);   // [N, H*64] bf16
    int* e_idx = (int*)(hb + (size_t)N_NODES * HEADS * OUT_DIM);      // [N, MAX_E]
    int* e_cnt = e_idx + (size_t)N_NODES * MAX_E;                     // [N]

    gat_proj_scan<<<PROJ_BLOCKS + N_NODES, 256, 0, stream>>>(
        x, W, adj, a_src, a_dst, hb, fsrc, fdst, e_idx, e_cnt);
    gat_agg<<<N_NODES, 256, 0, stream>>>(e_idx, e_cnt, hb, fsrc, fdst, out);
}